// Round 16
// baseline (735.289 us; speedup 1.0000x reference)
//
#include <hip/hip_runtime.h>
#include <math.h>

// Sinkhorn loss, B=8, S=2048, P=1024, D=2, eps=0.01, 50 iters.
// PERSISTENT-KERNEL v16 — v15 + __launch_bounds__(1024,4) spill fix.
// R15 diagnosis: exact-LSE restructure SPILLED — VGPR pinned 64 (compiler
// targeted 8 waves/SIMD occupancy absent a min-waves hint), live set ~90+
// => WRITE 13.6->41MB, FETCH 2.7->13.9MB scratch traffic, 723us. v16
// declares (1024,4) = our true occupancy (16 waves, 1 blk/CU) raising the
// VGPR cap to 128; the v15 inner loops (f: all 8 pairs in regs, one exact
// LSE, no rescale; g: 2 chunks of 8, 1 rescale) then run unspilled.
// Everything else = R13/v15 verbatim (XCD-local mapping, R7 barrier).
// Base-2 scaled potentials: F2 = f/(eps*ln2), G2 = g/(eps*ln2), K = 100*log2(e)
//   f elem: u = 2K*x.y + (G2[p] - K*y2[p]);  F2 = (K*x2 - log2 S) - LSE2(u)
//   g elem: u = 2K*x.y + (F2[s] - K*x2[s]);  G2 = (K*y2 + logb2) - LSE2(u)

#define BB 8
#define SS 2048
#define PP 1024
#define NEG_INF -1e9f
#define LOG2S 11.0f
#define ITERS 50
#define K2E 144.269504088896f   /* 100*log2(e) */
#define TWOK 288.539008177792f  /* 200*log2(e) */
#define NBLK 256
#define NTHR 1024

typedef float v2f __attribute__((ext_vector_type(2)));

__device__ __forceinline__ float fexp2(float x) {
  return __builtin_amdgcn_exp2f(x);
}
__device__ __forceinline__ float flog2(float x) {
  return __builtin_amdgcn_logf(x);
}
__device__ __forceinline__ v2f vfma(v2f a, v2f b, v2f c) {
  return __builtin_elementwise_fma(a, b, c);
}
__device__ __forceinline__ v2f vmax(v2f a, v2f b) {
  return __builtin_elementwise_max(a, b);
}

// agent-scope coherent (cache-bypassing) accessors, RELAXED only (proven R6+)
__device__ __forceinline__ float coh_load(const float* p) {
  return __hip_atomic_load((float*)p, __ATOMIC_RELAXED, __HIP_MEMORY_SCOPE_AGENT);
}
__device__ __forceinline__ void coh_store(float* p, float v) {
  __hip_atomic_store(p, v, __ATOMIC_RELAXED, __HIP_MEMORY_SCOPE_AGENT);
}
__device__ __forceinline__ int coh_loadi(const int* p) {
  return __hip_atomic_load((int*)p, __ATOMIC_RELAXED, __HIP_MEMORY_SCOPE_AGENT);
}
__device__ __forceinline__ void coh_storei(int* p, int v) {
  __hip_atomic_store(p, v, __ATOMIC_RELAXED, __HIP_MEMORY_SCOPE_AGENT);
}

// 32-block per-batch barrier, RMW-free (proven R7/R13): block stores its phase
// to its own slot; wave 0 polls the 32 slots (one per lane) until __all.
__device__ __forceinline__ void batch_barrier(int* slots, int sub, int phase,
                                              int w, int lane) {
  __syncthreads();
  asm volatile("" ::: "memory");
  if (threadIdx.x == 0) coh_storei(&slots[sub], phase);
  if (w == 0) {
    for (;;) {
      int v = (lane < 32) ? coh_loadi(&slots[lane]) : 0x7fffffff;
      if (__all(v >= phase)) break;
      __builtin_amdgcn_s_sleep(1);
    }
  }
  asm volatile("" ::: "memory");
  __syncthreads();
}

// ws layout (bytes):
//   G2    : [0,      32768)   B*P float
//   F2    : [32768,  98304)   B*S float
//   logb2 : [98304, 131072)   B*P float
//   slots : [131072, 132096)  8 batches x 32 ints (phase slots)

__global__ __launch_bounds__(1024) void setup_kernel(
    const int* __restrict__ labels, float* __restrict__ G2,
    float* __restrict__ logb2, int* __restrict__ slots,
    float* __restrict__ out) {
  __shared__ int c[PP];
  int b = blockIdx.x;
  int t = threadIdx.x;  // 1024 threads
  c[t] = 0;
  __syncthreads();
  atomicAdd(&c[labels[b * SS + t] & (PP - 1)], 1);
  atomicAdd(&c[labels[b * SS + PP + t] & (PP - 1)], 1);
  __syncthreads();
  int cc = c[t];
  logb2[b * PP + t] = (cc > 0) ? (flog2((float)cc) - LOG2S) : NEG_INF;
  G2[b * PP + t] = 0.0f;
  if (t < 32) slots[(b << 5) + t] = 0;
  if (t == 0 && b == 0) out[0] = 0.0f;
}

__global__ __launch_bounds__(1024, 4) void sinkhorn_persist(
    const float* __restrict__ preds, const float* __restrict__ pos,
    const float* __restrict__ logb2, float* __restrict__ F2g,
    float* __restrict__ G2g, int* __restrict__ slots,
    float* __restrict__ out) {
  // SoA LDS tiles: element-pair reads are pk-ready reg pairs (R9)
  __shared__ __align__(16) float fy0[PP], fy1[PP], fq[PP];        // 12 KB
  __shared__ __align__(16) float gx0[SS], gx1[SS], gq[SS];        // 24 KB
  __shared__ float spart;
  const int t = threadIdx.x;    // 1024 threads, 16 waves
  const int blk = blockIdx.x;   // 256 blocks = 1/CU (proven geometry)
  const int bb = blk & 7;       // XCD-LOCAL: batch = blk%8 (blk%8 = XCD)
  const int sub = blk >> 3;     // 32 blocks per batch, all on one XCD
  int* myslots = slots + (bb << 5);
  const float2* pos2 = (const float2*)pos;
  const float2* preds2 = (const float2*)preds;
  float* G2b = G2g + (bb << 10);
  float* F2b = F2g + (bb << 11);

  // ---- persistent init: x/y constants into LDS + K-scaled norms in regs
  float yr2, xr2[2];
  {
    float2 y = pos2[(bb << 10) + t];
    yr2 = y.x * y.x + y.y * y.y;
    fy0[t] = y.x;
    fy1[t] = y.y;
  }
#pragma unroll
  for (int k = 0; k < 2; ++k) {
    int e = t + (k << 10);
    float2 x = preds2[(bb << 11) + e];
    xr2[k] = x.x * x.x + x.y * x.y;
    gx0[e] = x.x;
    gx1[e] = x.y;
  }

  const int w = t >> 6, lane = t & 63;
  // f-phase: wave w owns 4 rows; lane holds all 8 elem-pairs in regs
  const int frowb = (bb << 11) + (sub << 6) + (w << 2);
  float fk0[4], fk1[4], fc0[4];
#pragma unroll
  for (int r = 0; r < 4; ++r) {
    float2 fx = preds2[frowb + r];  // wave-uniform broadcast load
    fk0[r] = TWOK * fx.x;
    fk1[r] = TWOK * fx.y;
    fc0[r] = fmaf(K2E, fx.x * fx.x + fx.y * fx.y, -LOG2S);
  }
  // g-phase: wave w owns 2 cols; lane scans 16 elem-pairs in 2 chunks of 8
  const int gcolb = (bb << 10) + (sub << 5) + (w << 1);
  float gk0[2], gk1[2], gc0[2];
#pragma unroll
  for (int c = 0; c < 2; ++c) {
    float2 gy = pos2[gcolb + c];
    gk0[c] = TWOK * gy.x;
    gk1[c] = TWOK * gy.y;
    gc0[c] = fmaf(K2E, gy.x * gy.x + gy.y * gy.y, logb2[gcolb + c]);
  }

  for (int it = 0; it < ITERS; ++it) {
    // ---- stage qy = G2 - K*y2 (4KB agent-scope reads, stride-1 LDS writes)
    fq[t] = fmaf(-K2E, yr2, coh_load(&G2b[t]));
    __syncthreads();
    // ---- f-compute: single-chunk exact LSE, all operands live in regs
    {
      v2f a0[8], a1[8], aq[8];
#pragma unroll
      for (int i = 0; i < 8; ++i) {
        int pi = (i << 6) + lane;  // pair index, consecutive lanes
        a0[i] = *(const v2f*)&fy0[pi << 1];
        a1[i] = *(const v2f*)&fy1[pi << 1];
        aq[i] = *(const v2f*)&fq[pi << 1];
      }
      float fout = 0.0f;
#pragma unroll
      for (int r = 0; r < 4; ++r) {
        v2f K0 = (v2f)(fk0[r]), K1 = (v2f)(fk1[r]);
        v2f u[8];
#pragma unroll
        for (int i = 0; i < 8; ++i)
          u[i] = vfma(K0, a0[i], vfma(K1, a1[i], aq[i]));
        v2f tt = vmax(vmax(vmax(u[0], u[1]), vmax(u[2], u[3])),
                      vmax(vmax(u[4], u[5]), vmax(u[6], u[7])));
        float M = fmaxf(tt.x, tt.y);
#pragma unroll
        for (int off = 1; off <= 32; off <<= 1)
          M = fmaxf(M, __shfl_xor(M, off, 64));
        v2f M2 = (v2f)(M);
        v2f es = (v2f)(0.0f);
#pragma unroll
        for (int i = 0; i < 8; ++i) {
          v2f d = u[i] - M2;
          es += (v2f){fexp2(d.x), fexp2(d.y)};
        }
        float S = es.x + es.y;
#pragma unroll
        for (int off = 1; off <= 32; off <<= 1) S += __shfl_xor(S, off, 64);
        float v = fc0[r] - M - flog2(S);
        if (lane == r) fout = v;
      }
      if (lane < 4) coh_store(&F2g[frowb + lane], fout);
    }
    batch_barrier(myslots, sub, 2 * it + 1, w, lane);

    // ---- stage qx = F2 - K*x2 (8KB agent-scope reads)
#pragma unroll
    for (int k = 0; k < 2; ++k) {
      int e = t + (k << 10);
      gq[e] = fmaf(-K2E, xr2[k], coh_load(&F2b[e]));
    }
    __syncthreads();
    // ---- g-compute: online LSE, 2 chunks of 8 pairs, 2 cols/lane
    {
      float m[2];
      v2f s[2];
#pragma unroll
      for (int c = 0; c < 2; ++c) { m[c] = -3.4e38f; s[c] = (v2f)(0.0f); }
#pragma unroll
      for (int ch = 0; ch < 2; ++ch) {
        v2f a0[8], a1[8], aq[8];
#pragma unroll
        for (int i = 0; i < 8; ++i) {
          int pi = (ch << 9) + (i << 6) + lane;
          a0[i] = *(const v2f*)&gx0[pi << 1];
          a1[i] = *(const v2f*)&gx1[pi << 1];
          aq[i] = *(const v2f*)&gq[pi << 1];
        }
#pragma unroll
        for (int c = 0; c < 2; ++c) {
          v2f K0 = (v2f)(gk0[c]), K1 = (v2f)(gk1[c]);
          v2f u[8];
#pragma unroll
          for (int i = 0; i < 8; ++i)
            u[i] = vfma(K0, a0[i], vfma(K1, a1[i], aq[i]));
          v2f tt = vmax(vmax(vmax(u[0], u[1]), vmax(u[2], u[3])),
                        vmax(vmax(u[4], u[5]), vmax(u[6], u[7])));
          float mn = fmaxf(m[c], fmaxf(tt.x, tt.y));
          float sc = fexp2(m[c] - mn);
          v2f mn2 = (v2f)(mn);
          v2f es = (v2f)(0.0f);
#pragma unroll
          for (int i = 0; i < 8; ++i) {
            v2f d = u[i] - mn2;
            es += (v2f){fexp2(d.x), fexp2(d.y)};
          }
          s[c] = vfma(s[c], (v2f)(sc), es);
          m[c] = mn;
        }
      }
      float gout = 0.0f;
#pragma unroll
      for (int c = 0; c < 2; ++c) {
        float M = m[c];
#pragma unroll
        for (int off = 1; off <= 32; off <<= 1)
          M = fmaxf(M, __shfl_xor(M, off, 64));
        float sr = (s[c].x + s[c].y) * fexp2(m[c] - M);
#pragma unroll
        for (int off = 1; off <= 32; off <<= 1) sr += __shfl_xor(sr, off, 64);
        float v = gc0[c] - M - flog2(sr);
        if (lane == c) gout = v;
      }
      if (lane < 2) coh_store(&G2g[gcolb + lane], gout);
    }
    batch_barrier(myslots, sub, 2 * it + 2, w, lane);
  }

  // ---- fused final: restage qy with final G2, rowsum over own 64 rows
  if (t == 0) spart = 0.0f;
  fq[t] = fmaf(-K2E, yr2, coh_load(&G2b[t]));
  __syncthreads();
  float acc = 0.0f;
#pragma unroll
  for (int rr = 0; rr < 4; ++rr) {
    int row = frowb + rr;
    float2 x = preds2[row];
    float x2 = x.x * x.x + x.y * x.y;
    float qx = fmaf(-K2E, x2, coh_load(&F2g[row]));
#pragma unroll
    for (int i = 0; i < 16; ++i) {
      int p = (i << 6) + lane;
      float ay0 = fy0[p], ay1 = fy1[p], aqz = fq[p];
      float y2 = fmaf(ay0, ay0, ay1 * ay1);
      float tt = fmaf(x.y, ay1, x.x * ay0);
      float c = fmaxf(x2 + y2 - 2.0f * tt, 0.0f);  // clamped cost
      float v2 = fmaf(TWOK, tt, aqz + qx);         // -K*C' + F2 + G2 (base-2)
      acc = fmaf(fexp2(v2), c, acc);               // c==0 kills C'<0 case
    }
  }
#pragma unroll
  for (int off = 32; off; off >>= 1) acc += __shfl_xor(acc, off, 64);
  if (lane == 0) atomicAdd(&spart, acc);
  __syncthreads();
  if (t == 0) atomicAdd(out, spart * (1.0f / (float)BB));
}

extern "C" void kernel_launch(void* const* d_in, const int* in_sizes, int n_in,
                              void* d_out, int out_size, void* d_ws,
                              size_t ws_size, hipStream_t stream) {
  const float* preds = (const float*)d_in[0];  // [B,S,2]
  const int* labels = (const int*)d_in[1];     // [B,S]
  const float* pos = (const float*)d_in[2];    // [B,P,2]
  float* out = (float*)d_out;
  char* ws = (char*)d_ws;
  float* G2 = (float*)(ws);
  float* F2 = (float*)(ws + 32768);
  float* logb2 = (float*)(ws + 98304);
  int* slots = (int*)(ws + 131072);

  hipLaunchKernelGGL(setup_kernel, dim3(BB), dim3(1024), 0, stream, labels, G2,
                     logb2, slots, out);
  hipLaunchKernelGGL(sinkhorn_persist, dim3(NBLK), dim3(NTHR), 0, stream,
                     preds, pos, logb2, F2, G2, slots, out);
}

// Round 17
// 548.719 us; speedup vs baseline: 1.3400x; 1.3400x over previous
//
#include <hip/hip_runtime.h>
#include <math.h>

// Sinkhorn loss, B=8, S=2048, P=1024, D=2, eps=0.01, 50 iters.
// PERSISTENT-KERNEL FINAL — restore R13 (550us, session best; 1.53x the
// 844us multi-launch baseline).
// Session ledger: persistent kernel + per-batch RMW-free store/poll barrier
// (R7) + SoA LDS & packed-f32 pk math (R9) + XCD-local batch mapping (R13:
// batch=blk&7 keeps each batch's exchange inside one XCD's L2 — FETCH
// 21->2.7MB). Falsified axes: occupancy >4 waves/SIMD (R8: 1024thr/50KB
// never dual-occupies), dual-batch interleave (R10/R12: phase bloat or
// cache thrash), stamped dataflow sync (R11: poll re-fetch traffic),
// barrier padding/sleep (R14: flat), exact-LSE restructure (R15/R16:
// compiler pins 64 VGPR at 1024thr -> spills, 2x tested).
// Structural floor: ~295us VALU (fma+exp+butterfly mix) + 100 serialized
// cross-CU sync settles x ~1.25us + staging/skew ~= 550us.
// Base-2 scaled potentials: F2 = f/(eps*ln2), G2 = g/(eps*ln2), K = 100*log2(e)
//   f elem: u = 2K*x.y + (G2[p] - K*y2[p]);  F2 = (K*x2 - log2 S) - LSE2(u)
//   g elem: u = 2K*x.y + (F2[s] - K*x2[s]);  G2 = (K*y2 + logb2) - LSE2(u)

#define BB 8
#define SS 2048
#define PP 1024
#define NEG_INF -1e9f
#define LOG2S 11.0f
#define ITERS 50
#define K2E 144.269504088896f   /* 100*log2(e) */
#define TWOK 288.539008177792f  /* 200*log2(e) */
#define NBLK 256
#define NTHR 1024

typedef float v2f __attribute__((ext_vector_type(2)));

__device__ __forceinline__ float fexp2(float x) {
  return __builtin_amdgcn_exp2f(x);
}
__device__ __forceinline__ float flog2(float x) {
  return __builtin_amdgcn_logf(x);
}
__device__ __forceinline__ v2f vfma(v2f a, v2f b, v2f c) {
  return __builtin_elementwise_fma(a, b, c);
}
__device__ __forceinline__ v2f vmax(v2f a, v2f b) {
  return __builtin_elementwise_max(a, b);
}

// agent-scope coherent (cache-bypassing) accessors, RELAXED only (proven R6+)
__device__ __forceinline__ float coh_load(const float* p) {
  return __hip_atomic_load((float*)p, __ATOMIC_RELAXED, __HIP_MEMORY_SCOPE_AGENT);
}
__device__ __forceinline__ void coh_store(float* p, float v) {
  __hip_atomic_store(p, v, __ATOMIC_RELAXED, __HIP_MEMORY_SCOPE_AGENT);
}
__device__ __forceinline__ int coh_loadi(const int* p) {
  return __hip_atomic_load((int*)p, __ATOMIC_RELAXED, __HIP_MEMORY_SCOPE_AGENT);
}
__device__ __forceinline__ void coh_storei(int* p, int v) {
  __hip_atomic_store(p, v, __ATOMIC_RELAXED, __HIP_MEMORY_SCOPE_AGENT);
}

// 32-block per-batch barrier, RMW-free (proven R7/R13): block stores its phase
// to its own slot; wave 0 polls the 32 slots (one per lane) until __all.
__device__ __forceinline__ void batch_barrier(int* slots, int sub, int phase,
                                              int w, int lane) {
  __syncthreads();
  asm volatile("" ::: "memory");
  if (threadIdx.x == 0) coh_storei(&slots[sub], phase);
  if (w == 0) {
    for (;;) {
      int v = (lane < 32) ? coh_loadi(&slots[lane]) : 0x7fffffff;
      if (__all(v >= phase)) break;
      __builtin_amdgcn_s_sleep(1);
    }
  }
  asm volatile("" ::: "memory");
  __syncthreads();
}

// ws layout (bytes):
//   G2    : [0,      32768)   B*P float
//   F2    : [32768,  98304)   B*S float
//   logb2 : [98304, 131072)   B*P float
//   slots : [131072, 132096)  8 batches x 32 ints (phase slots)

__global__ __launch_bounds__(1024) void setup_kernel(
    const int* __restrict__ labels, float* __restrict__ G2,
    float* __restrict__ logb2, int* __restrict__ slots,
    float* __restrict__ out) {
  __shared__ int c[PP];
  int b = blockIdx.x;
  int t = threadIdx.x;  // 1024 threads
  c[t] = 0;
  __syncthreads();
  atomicAdd(&c[labels[b * SS + t] & (PP - 1)], 1);
  atomicAdd(&c[labels[b * SS + PP + t] & (PP - 1)], 1);
  __syncthreads();
  int cc = c[t];
  logb2[b * PP + t] = (cc > 0) ? (flog2((float)cc) - LOG2S) : NEG_INF;
  G2[b * PP + t] = 0.0f;
  if (t < 32) slots[(b << 5) + t] = 0;
  if (t == 0 && b == 0) out[0] = 0.0f;
}

__global__ __launch_bounds__(1024) void sinkhorn_persist(
    const float* __restrict__ preds, const float* __restrict__ pos,
    const float* __restrict__ logb2, float* __restrict__ F2g,
    float* __restrict__ G2g, int* __restrict__ slots,
    float* __restrict__ out) {
  // SoA LDS tiles: element-pair reads are pk-ready reg pairs (R9)
  __shared__ __align__(16) float fy0[PP], fy1[PP], fq[PP];        // 12 KB
  __shared__ __align__(16) float gx0[SS], gx1[SS], gq[SS];        // 24 KB
  __shared__ float spart;
  const int t = threadIdx.x;    // 1024 threads, 16 waves
  const int blk = blockIdx.x;   // 256 blocks = 1/CU (proven geometry)
  const int bb = blk & 7;       // XCD-LOCAL: batch = blk%8 (blk%8 = XCD)
  const int sub = blk >> 3;     // 32 blocks per batch, all on one XCD
  int* myslots = slots + (bb << 5);
  const float2* pos2 = (const float2*)pos;
  const float2* preds2 = (const float2*)preds;
  float* G2b = G2g + (bb << 10);
  float* F2b = F2g + (bb << 11);

  // ---- persistent init: x/y constants into LDS + K-scaled norms in regs
  float yr2, xr2[2];
  {
    float2 y = pos2[(bb << 10) + t];
    yr2 = y.x * y.x + y.y * y.y;
    fy0[t] = y.x;
    fy1[t] = y.y;
  }
#pragma unroll
  for (int k = 0; k < 2; ++k) {
    int e = t + (k << 10);
    float2 x = preds2[(bb << 11) + e];
    xr2[k] = x.x * x.x + x.y * x.y;
    gx0[e] = x.x;
    gx1[e] = x.y;
  }

  const int w = t >> 6, lane = t & 63;
  // f-phase: wave w owns 4 rows; lane scans 8 elem-pairs (global row index)
  const int frowb = (bb << 11) + (sub << 6) + (w << 2);
  float fk0[4], fk1[4], fc0[4];
#pragma unroll
  for (int r = 0; r < 4; ++r) {
    float2 fx = preds2[frowb + r];  // wave-uniform broadcast load
    fk0[r] = TWOK * fx.x;
    fk1[r] = TWOK * fx.y;
    fc0[r] = fmaf(K2E, fx.x * fx.x + fx.y * fx.y, -LOG2S);
  }
  // g-phase: wave w owns 2 cols; lane scans 16 elem-pairs (global col index)
  const int gcolb = (bb << 10) + (sub << 5) + (w << 1);
  float gk0[2], gk1[2], gc0[2];
#pragma unroll
  for (int c = 0; c < 2; ++c) {
    float2 gy = pos2[gcolb + c];
    gk0[c] = TWOK * gy.x;
    gk1[c] = TWOK * gy.y;
    gc0[c] = fmaf(K2E, gy.x * gy.x + gy.y * gy.y, logb2[gcolb + c]);
  }

  for (int it = 0; it < ITERS; ++it) {
    // ---- stage qy = G2 - K*y2 (4KB agent-scope reads, stride-1 LDS writes)
    fq[t] = fmaf(-K2E, yr2, coh_load(&G2b[t]));
    __syncthreads();
    // ---- f-compute: online LSE over pairs, 4 rows/lane, pk math
    {
      float m[4];
      v2f s[4];
#pragma unroll
      for (int r = 0; r < 4; ++r) { m[r] = -3.4e38f; s[r] = (v2f)(0.0f); }
#pragma unroll
      for (int ch = 0; ch < 2; ++ch) {
        v2f a0[4], a1[4], aq[4];
#pragma unroll
        for (int i = 0; i < 4; ++i) {
          int pi = (ch << 8) + (i << 6) + lane;  // pair index, consecutive
          a0[i] = *(const v2f*)&fy0[pi << 1];
          a1[i] = *(const v2f*)&fy1[pi << 1];
          aq[i] = *(const v2f*)&fq[pi << 1];
        }
#pragma unroll
        for (int r = 0; r < 4; ++r) {
          v2f K0 = (v2f)(fk0[r]), K1 = (v2f)(fk1[r]);
          v2f u0 = vfma(K0, a0[0], vfma(K1, a1[0], aq[0]));
          v2f u1 = vfma(K0, a0[1], vfma(K1, a1[1], aq[1]));
          v2f u2 = vfma(K0, a0[2], vfma(K1, a1[2], aq[2]));
          v2f u3 = vfma(K0, a0[3], vfma(K1, a1[3], aq[3]));
          v2f cm2 = vmax(vmax(u0, u1), vmax(u2, u3));
          float mn = fmaxf(m[r], fmaxf(cm2.x, cm2.y));
          float sc = fexp2(m[r] - mn);
          v2f mn2 = (v2f)(mn);
          v2f d0 = u0 - mn2, d1 = u1 - mn2, d2 = u2 - mn2, d3 = u3 - mn2;
          v2f e0 = {fexp2(d0.x), fexp2(d0.y)};
          v2f e1 = {fexp2(d1.x), fexp2(d1.y)};
          v2f e2 = {fexp2(d2.x), fexp2(d2.y)};
          v2f e3 = {fexp2(d3.x), fexp2(d3.y)};
          s[r] = vfma(s[r], (v2f)(sc), (e0 + e1) + (e2 + e3));
          m[r] = mn;
        }
      }
      // lane merge; lane r keeps value r; lanes 0..3 store coalesced
      float fout = 0.0f;
#pragma unroll
      for (int r = 0; r < 4; ++r) {
        float M = m[r];
#pragma unroll
        for (int off = 1; off <= 32; off <<= 1)
          M = fmaxf(M, __shfl_xor(M, off, 64));
        float sr = (s[r].x + s[r].y) * fexp2(m[r] - M);
#pragma unroll
        for (int off = 1; off <= 32; off <<= 1) sr += __shfl_xor(sr, off, 64);
        float v = fc0[r] - M - flog2(sr);
        if (lane == r) fout = v;
      }
      if (lane < 4) coh_store(&F2g[frowb + lane], fout);
    }
    batch_barrier(myslots, sub, 2 * it + 1, w, lane);

    // ---- stage qx = F2 - K*x2 (8KB agent-scope reads)
#pragma unroll
    for (int k = 0; k < 2; ++k) {
      int e = t + (k << 10);
      gq[e] = fmaf(-K2E, xr2[k], coh_load(&F2b[e]));
    }
    __syncthreads();
    // ---- g-compute: online LSE over pairs, 2 cols/lane, pk math
    {
      float m[2];
      v2f s[2];
#pragma unroll
      for (int c = 0; c < 2; ++c) { m[c] = -3.4e38f; s[c] = (v2f)(0.0f); }
#pragma unroll
      for (int ch = 0; ch < 4; ++ch) {
        v2f a0[4], a1[4], aq[4];
#pragma unroll
        for (int i = 0; i < 4; ++i) {
          int pi = (ch << 8) + (i << 6) + lane;
          a0[i] = *(const v2f*)&gx0[pi << 1];
          a1[i] = *(const v2f*)&gx1[pi << 1];
          aq[i] = *(const v2f*)&gq[pi << 1];
        }
#pragma unroll
        for (int c = 0; c < 2; ++c) {
          v2f K0 = (v2f)(gk0[c]), K1 = (v2f)(gk1[c]);
          v2f u0 = vfma(K0, a0[0], vfma(K1, a1[0], aq[0]));
          v2f u1 = vfma(K0, a0[1], vfma(K1, a1[1], aq[1]));
          v2f u2 = vfma(K0, a0[2], vfma(K1, a1[2], aq[2]));
          v2f u3 = vfma(K0, a0[3], vfma(K1, a1[3], aq[3]));
          v2f cm2 = vmax(vmax(u0, u1), vmax(u2, u3));
          float mn = fmaxf(m[c], fmaxf(cm2.x, cm2.y));
          float sc = fexp2(m[c] - mn);
          v2f mn2 = (v2f)(mn);
          v2f d0 = u0 - mn2, d1 = u1 - mn2, d2 = u2 - mn2, d3 = u3 - mn2;
          v2f e0 = {fexp2(d0.x), fexp2(d0.y)};
          v2f e1 = {fexp2(d1.x), fexp2(d1.y)};
          v2f e2 = {fexp2(d2.x), fexp2(d2.y)};
          v2f e3 = {fexp2(d3.x), fexp2(d3.y)};
          s[c] = vfma(s[c], (v2f)(sc), (e0 + e1) + (e2 + e3));
          m[c] = mn;
        }
      }
      float gout = 0.0f;
#pragma unroll
      for (int c = 0; c < 2; ++c) {
        float M = m[c];
#pragma unroll
        for (int off = 1; off <= 32; off <<= 1)
          M = fmaxf(M, __shfl_xor(M, off, 64));
        float sr = (s[c].x + s[c].y) * fexp2(m[c] - M);
#pragma unroll
        for (int off = 1; off <= 32; off <<= 1) sr += __shfl_xor(sr, off, 64);
        float v = gc0[c] - M - flog2(sr);
        if (lane == c) gout = v;
      }
      if (lane < 2) coh_store(&G2g[gcolb + lane], gout);
    }
    batch_barrier(myslots, sub, 2 * it + 2, w, lane);
  }

  // ---- fused final: restage qy with final G2, rowsum over own 64 rows
  if (t == 0) spart = 0.0f;
  fq[t] = fmaf(-K2E, yr2, coh_load(&G2b[t]));
  __syncthreads();
  float acc = 0.0f;
#pragma unroll
  for (int rr = 0; rr < 4; ++rr) {
    int row = frowb + rr;
    float2 x = preds2[row];
    float x2 = x.x * x.x + x.y * x.y;
    float qx = fmaf(-K2E, x2, coh_load(&F2g[row]));
#pragma unroll
    for (int i = 0; i < 16; ++i) {
      int p = (i << 6) + lane;
      float ay0 = fy0[p], ay1 = fy1[p], aqz = fq[p];
      float y2 = fmaf(ay0, ay0, ay1 * ay1);
      float tt = fmaf(x.y, ay1, x.x * ay0);
      float c = fmaxf(x2 + y2 - 2.0f * tt, 0.0f);  // clamped cost
      float v2 = fmaf(TWOK, tt, aqz + qx);         // -K*C' + F2 + G2 (base-2)
      acc = fmaf(fexp2(v2), c, acc);               // c==0 kills C'<0 case
    }
  }
#pragma unroll
  for (int off = 32; off; off >>= 1) acc += __shfl_xor(acc, off, 64);
  if (lane == 0) atomicAdd(&spart, acc);
  __syncthreads();
  if (t == 0) atomicAdd(out, spart * (1.0f / (float)BB));
}

extern "C" void kernel_launch(void* const* d_in, const int* in_sizes, int n_in,
                              void* d_out, int out_size, void* d_ws,
                              size_t ws_size, hipStream_t stream) {
  const float* preds = (const float*)d_in[0];  // [B,S,2]
  const int* labels = (const int*)d_in[1];     // [B,S]
  const float* pos = (const float*)d_in[2];    // [B,P,2]
  float* out = (float*)d_out;
  char* ws = (char*)d_ws;
  float* G2 = (float*)(ws);
  float* F2 = (float*)(ws + 32768);
  float* logb2 = (float*)(ws + 98304);
  int* slots = (int*)(ws + 131072);

  hipLaunchKernelGGL(setup_kernel, dim3(BB), dim3(1024), 0, stream, labels, G2,
                     logb2, slots, out);
  hipLaunchKernelGGL(sinkhorn_persist, dim3(NBLK), dim3(NTHR), 0, stream,
                     preds, pos, logb2, F2, G2, slots, out);
}